// Round 11
// baseline (6097.173 us; speedup 1.0000x reference)
//
#include <hip/hip_runtime.h>
#include <hip/hip_bf16.h>
#include <math.h>

#define B_ 128
#define S_ 512
#define D_ 256
#define H_ 512
#define E_ 256
#define V_ 1002
#define T_ 34
#define END_ 1001
#define NWG_LAUNCH 256   // 32 per XCD-hint; hints 0..3 work, 4..7 exit
#define BH (B_ * H_)     // one h-history slot: 65536 elems (128 KB)
#define HROWB 1040       // LDS h tile row pitch (bytes)
#define GPITCH 20        // gbuf row pitch (dwords), 80B

typedef __attribute__((ext_vector_type(8))) short short8;
typedef __attribute__((ext_vector_type(4))) float f32x4;
typedef __attribute__((ext_vector_type(4))) int i32x4;
typedef unsigned long long u64;

__device__ __forceinline__ float bf2f(unsigned short u){
  union { unsigned int i; float f; } x; x.i = ((unsigned int)u) << 16; return x.f;
}
__device__ __forceinline__ unsigned short f2bf(float f){
  union { float f; unsigned int i; } x; x.f = f;
  unsigned int r = x.i + 0x7fffu + ((x.i >> 16) & 1u);
  return (unsigned short)(r >> 16);
}
__device__ __forceinline__ float sigm(float x){ return 1.0f / (1.0f + expf(-x)); }

// dual store: normal write-back (feeds same-XCD readers from local L2) +
// sc0sc1 write-through (MALL truth for remote readers / fallback).
// Write-once buffers + identical values => any ordering/eviction is benign.
__device__ __forceinline__ void store_dual8(unsigned short* p, u64 v){
  asm volatile("global_store_dwordx2 %0, %1, off"         :: "v"(p), "v"(v) : "memory");
  asm volatile("global_store_dwordx2 %0, %1, off sc0 sc1" :: "v"(p), "v"(v) : "memory");
}

// wide coherent flag read: one 16B MALL load (flags are multi-writer lines,
// so polls must bypass L2 -- MALL is the single source of truth)
__device__ __forceinline__ i32x4 load_flags16(const unsigned* p){
  i32x4 r;
  asm volatile("global_load_dwordx4 %0, %1, off sc0 sc1\n\ts_waitcnt vmcnt(0)"
               : "=v"(r) : "v"(p) : "memory");
  return r;
}

// stage the 64-row x 1024-B h tile into LDS (HROWB pitch) with sc0-only
// loads: bypass L1, hit local L2 when producer is co-located, else fill
// from MALL (first toucher per XCD; subsequent WGs L2-hit).
__device__ __forceinline__ void stage_tile_l2(const unsigned short* src, char* dst, int tid){
  i32x4 r[16];
  #pragma unroll
  for (int p = 0; p < 16; ++p){
    const char* sp = (const char*)src + p * 4096 + tid * 16;
    asm volatile("global_load_dwordx4 %0, %1, off sc0" : "=v"(r[p]) : "v"(sp));
  }
  asm volatile("s_waitcnt vmcnt(0)" ::: "memory");
  #pragma unroll
  for (int p = 0; p < 16; ++p){
    const int off = p * 4096 + tid * 16;
    *reinterpret_cast<i32x4*>(dst + (off >> 10) * HROWB + (off & 1023)) = r[p];
  }
}

// ---------------- conversion / setup kernels ----------------

__global__ void f2bf_kernel(const float* __restrict__ in, unsigned short* __restrict__ out, int n){
  int i = blockIdx.x * blockDim.x + threadIdx.x;
  int stride = gridDim.x * blockDim.x;
  for (; i < n; i += stride) out[i] = f2bf(in[i]);
}

__global__ void embed_kernel(const float* __restrict__ emb, const int* __restrict__ ids,
                             unsigned short* __restrict__ out){
  int i = blockIdx.x * blockDim.x + threadIdx.x;
  if (i >= B_ * T_ * E_) return;
  int bt = i >> 8;              // E_=256
  int e  = i & (E_ - 1);
  out[i] = f2bf(emb[(size_t)ids[bt] * E_ + e]);
}

// Wcat layout: [2048, K], K = Din + H. Row n = g*512 + j:
//   g=0 (r): [Wih_r | Whh_r]   g=1 (z): [Wih_z | Whh_z]
//   g=2 (n_input): [Wih_n | 0] g=3 (n_hidden): [0 | Whh_n]
__global__ void build_wcat(const float* __restrict__ Wih, const float* __restrict__ Whh,
                           unsigned short* __restrict__ Wcat, int Din){
  int K = Din + H_;
  int total = 2048 * K;
  int i = blockIdx.x * blockDim.x + threadIdx.x;
  int stride = gridDim.x * blockDim.x;
  for (; i < total; i += stride){
    int n = i / K, k = i - n * K;
    int g = n >> 9, j = n & 511;
    float v;
    if (g < 2){
      int r = (g << 9) + j;
      v = (k < Din) ? Wih[(size_t)r * Din + k] : Whh[(size_t)r * H_ + (k - Din)];
    } else if (g == 2){
      v = (k < Din) ? Wih[(size_t)(1024 + j) * Din + k] : 0.0f;
    } else {
      v = (k < Din) ? 0.0f : Whh[(size_t)(1024 + j) * H_ + (k - Din)];
    }
    Wcat[i] = f2bf(v);
  }
}

// bias4: [2048] = {bih_r+bhh_r, bih_z+bhh_z, bih_n, bhh_n}
__global__ void build_bias(const float* __restrict__ bih, const float* __restrict__ bhh,
                           float* __restrict__ out){
  int j = blockIdx.x * blockDim.x + threadIdx.x;
  if (j >= 512) return;
  out[j]        = bih[j] + bhh[j];
  out[512 + j]  = bih[512 + j] + bhh[512 + j];
  out[1024 + j] = bih[1024 + j];
  out[1536 + j] = bhh[1024 + j];
}

// ---------------- persistent RNN kernel ----------------
// 256 WGs launched; hint = wgid&7 (XCD under round-robin dispatch).
// hint 0..3 -> groups (L0/mh0, L0/mh1, L1/mh0, L1/mh1), jtile = wgid>>3;
// hint 4..7 exit. If round-robin holds, each 32-WG recurrence group is
// resident on ONE XCD and the h exchange is local-L2; correctness does
// NOT depend on placement (dual-store + MALL-truth flags).
// All dynamic state is write-once, t-indexed: H0/H1[547] slots
//   (slot 0 = zeros; enc t -> slot t+1; dec t -> 513+t; dec reads 512+t).
// Waves = K-quarters x all 4 gates; cross-wave K-reduction via
// gbuf[q][g][64][GPITCH]. Weights VGPR-resident per phase.
// h-prev carried in registers (thread owns 1 row x 4 cols).

template<int KT, int XKT>
__device__ __forceinline__ void run_layer(
    char* smem,
    const unsigned short* __restrict__ Wc, const float* __restrict__ bias4,
    const unsigned short* __restrict__ Xbase, int x_rs, int x_ts,
    const unsigned short* __restrict__ Hread,  // slot t at Hread + t*BH
    unsigned short* Hwrite,                    // step t writes Hwrite + t*BH
    int T, unsigned round0,
    unsigned* own_flags, int slot,
    unsigned* prod_flags, unsigned prod0,      // nullable
    u64* hprev,
    int jtile, int mh, int wv, int lane)
{
  constexpr int K   = KT * 32;
  constexpr int KTL = KT / 4;          // kt-slices per wave
  const int tid  = threadIdx.x;
  const int ln   = lane & 15;
  const int lk8  = (lane >> 4) << 3;
  const int base_m = mh * 64;
  const int q = wv;                    // this wave's K-quarter

  char*  hA   = smem;                                   // [64][HROWB]
  float* gbuf = (float*)(smem + 64 * HROWB);            // [4q][4g][64][GPITCH]

  // ---- weights: 4 gates x 16 cols, K-slice [q*KTL*32, ...) ----
  short8 wreg[4][KTL];
  #pragma unroll
  for (int g = 0; g < 4; ++g)
    #pragma unroll
    for (int k = 0; k < KTL; ++k)
      wreg[g][k] = *reinterpret_cast<const short8*>(
          Wc + (size_t)(g * 512 + jtile * 16 + ln) * K + (size_t)(q * KTL + k) * 32 + lk8);

  // ---- epilogue ownership: thread = 1 row x 4 cols (one 8B h granule) ----
  const int erow  = tid >> 2;          // 0..63
  const int ecol0 = (tid & 3) << 2;    // 0,4,8,12
  const int ej    = (jtile << 4) + ecol0;
  const int egr   = base_m + erow;
  f32x4 bR, bZ, bNI, bNH;
  #pragma unroll
  for (int c = 0; c < 4; ++c){
    bR[c]  = bias4[ej + c];
    bZ[c]  = bias4[512 + ej + c];
    bNI[c] = bias4[1024 + ej + c];
    bNH[c] = bias4[1536 + ej + c];
  }

  for (int t = 0; t < T; ++t){
    // ---- wait: own group's h[t-1] slot complete + producer x slot ----
    if (wv == 0){
      const unsigned own_t  = round0 + (unsigned)t;
      const unsigned prod_t = prod0 + (unsigned)t + 1u;
      const unsigned* pofs = own_flags + (lane & 7) * 4;
      const unsigned* ppfs = prod_flags ? (prod_flags + (lane & 7) * 4) : nullptr;
      for (;;){
        i32x4 f = load_flags16(pofs);
        bool ok = (unsigned)f.x >= own_t && (unsigned)f.y >= own_t &&
                  (unsigned)f.z >= own_t && (unsigned)f.w >= own_t;
        if (ppfs){
          i32x4 g = load_flags16(ppfs);
          ok = ok && (unsigned)g.x >= prod_t && (unsigned)g.y >= prod_t &&
                     (unsigned)g.z >= prod_t && (unsigned)g.w >= prod_t;
        }
        if (__all(ok)) break;
        __builtin_amdgcn_s_sleep(1);
      }
    }
    __syncthreads();

    const unsigned short* Xt  = Xbase + (size_t)t * x_ts;
    const unsigned short* Hin = Hread + (size_t)t * BH;

    // ---- stage h tile to LDS (sc0: local-L2 fast path, MALL fallback) ----
    stage_tile_l2(Hin + ((size_t)base_m << 9), hA, tid);
    __syncthreads();

    // ---- MFMA K-loop: this wave's K-quarter, all 4 gates ----
    f32x4 acc[4][4];
    #pragma unroll
    for (int g = 0; g < 4; ++g)
      #pragma unroll
      for (int mt = 0; mt < 4; ++mt) acc[g][mt] = (f32x4){0.f, 0.f, 0.f, 0.f};

    #pragma unroll
    for (int k = 0; k < KTL; ++k){
      const int kt = q * KTL + k;
      short8 a[4];
      if (kt < XKT){
        #pragma unroll
        for (int mt = 0; mt < 4; ++mt)
          a[mt] = *reinterpret_cast<const short8*>(
              Xt + (size_t)(base_m + mt * 16 + ln) * x_rs + kt * 32 + lk8);
      } else {
        #pragma unroll
        for (int mt = 0; mt < 4; ++mt)
          a[mt] = *reinterpret_cast<const short8*>(
              hA + (mt * 16 + ln) * HROWB + ((kt - XKT) * 32 + lk8) * 2);
      }
      #pragma unroll
      for (int g = 0; g < 4; ++g)
        #pragma unroll
        for (int mt = 0; mt < 4; ++mt)
          acc[g][mt] = __builtin_amdgcn_mfma_f32_16x16x32_bf16(a[mt], wreg[g][k], acc[g][mt], 0, 0, 0);
    }

    // ---- partial sums to gbuf[q][g][row][col] ----
    #pragma unroll
    for (int g = 0; g < 4; ++g)
      #pragma unroll
      for (int mt = 0; mt < 4; ++mt){
        const int rl = mt * 16 + ((lane >> 4) << 2);
        #pragma unroll
        for (int i = 0; i < 4; ++i)
          gbuf[((q * 4 + g) * 64 + rl + i) * GPITCH + ln] = acc[g][mt][i];
      }
    __syncthreads();

    // ---- epilogue: sum K-quarters, GRU nonlinearity; h-prev register ----
    {
      f32x4 p0 = (f32x4){0.f,0.f,0.f,0.f}, p1 = p0, p2 = p0, p3 = p0;
      #pragma unroll
      for (int qq = 0; qq < 4; ++qq){
        p0 += *reinterpret_cast<const f32x4*>(gbuf + ((qq * 4 + 0) * 64 + erow) * GPITCH + ecol0);
        p1 += *reinterpret_cast<const f32x4*>(gbuf + ((qq * 4 + 1) * 64 + erow) * GPITCH + ecol0);
        p2 += *reinterpret_cast<const f32x4*>(gbuf + ((qq * 4 + 2) * 64 + erow) * GPITCH + ecol0);
        p3 += *reinterpret_cast<const f32x4*>(gbuf + ((qq * 4 + 3) * 64 + erow) * GPITCH + ecol0);
      }
      u64 hv = *hprev;
      u64 hb = 0;
      #pragma unroll
      for (int c = 0; c < 4; ++c){
        float rr = sigm(p0[c] + bR[c]);
        float zz = sigm(p1[c] + bZ[c]);
        float nn = tanhf(p2[c] + bNI[c] + rr * (p3[c] + bNH[c]));
        float hp = bf2f((unsigned short)(hv >> (16 * c)));
        float hn = (1.0f - zz) * nn + zz * hp;
        hb |= ((u64)f2bf(hn)) << (16 * c);
      }
      *hprev = hb;
      store_dual8(Hwrite + (size_t)t * BH + ((size_t)egr << 9) + ej, hb);
    }

    // ---- publish: drain both stores (local + MALL), then flag my slot ----
    asm volatile("s_waitcnt vmcnt(0)" ::: "memory");
    __syncthreads();
    if (tid == 0)
      __hip_atomic_store(own_flags + slot, round0 + (unsigned)t + 1u,
                         __ATOMIC_RELAXED, __HIP_MEMORY_SCOPE_AGENT);
  }
}

__global__ __launch_bounds__(256, 1)
void rnn_persistent(
    const unsigned short* __restrict__ src, const unsigned short* __restrict__ tg,
    const unsigned short* __restrict__ Wc_e0, const unsigned short* __restrict__ Wc_e1,
    const unsigned short* __restrict__ Wc_d0, const unsigned short* __restrict__ Wc_d1,
    const float* __restrict__ b_e0, const float* __restrict__ b_e1,
    const float* __restrict__ b_d0, const float* __restrict__ b_d1,
    unsigned short* H0, unsigned short* H1,
    unsigned* flags)
{
  __shared__ __align__(16) char smem[64 * HROWB + 16 * 64 * GPITCH * 4];  // 148 KB
  const int wg = blockIdx.x;
  const int hint = wg & 7;        // XCD under round-robin dispatch (perf-only)
  if (hint >= 4) return;          // idle hints exit immediately
  // one-time acquire: clear stale lines (poison / previous replay) from caches
  __builtin_amdgcn_fence(__ATOMIC_ACQUIRE, "agent");
  const int layer = hint >> 1;
  const int mh    = hint & 1;
  const int jtile = wg >> 3;      // 0..31
  const int wv = threadIdx.x >> 6, lane = threadIdx.x & 63;
  unsigned* own  = flags + (size_t)((layer << 1) | mh) * 64;
  unsigned* prod = flags + (size_t)mh * 64;     // layer-0 flags of same mh
  u64 hprev = 0;
  if (layer == 0){
    run_layer<24, 8>(smem, Wc_e0, b_e0, src, S_ * D_, D_,
                     H0, H0 + BH, S_, 0u, own, jtile, nullptr, 0u, &hprev,
                     jtile, mh, wv, lane);
    run_layer<24, 8>(smem, Wc_d0, b_d0, tg, T_ * E_, E_,
                     H0 + (size_t)512 * BH, H0 + (size_t)513 * BH, T_, 512u,
                     own, jtile, nullptr, 0u, &hprev,
                     jtile, mh, wv, lane);
  } else {
    run_layer<32, 16>(smem, Wc_e1, b_e1, H0 + BH, H_, BH,
                      H1, H1 + BH, S_, 0u, own, jtile, prod, 0u, &hprev,
                      jtile, mh, wv, lane);
    run_layer<32, 16>(smem, Wc_d1, b_d1, H0 + (size_t)513 * BH, H_, BH,
                      H1 + (size_t)512 * BH, H1 + (size_t)513 * BH, T_, 512u,
                      own, jtile, prod, 512u, &hprev,
                      jtile, mh, wv, lane);
  }
}

// ---------------- generic NT GEMM: C = act(A[M,K] @ W[N,K]^T + bias) ----------------
__global__ __launch_bounds__(256)
void gemm_nt(const unsigned short* __restrict__ A, const unsigned short* __restrict__ W,
             const float* __restrict__ bias,
             unsigned short* __restrict__ outB, float* __restrict__ outF,
             int M, int N, int K, int act)
{
  const int w    = threadIdx.x >> 6;
  const int lane = threadIdx.x & 63;
  const int ln   = lane & 15;
  const int lk8  = (lane >> 4) << 3;
  const int row0 = blockIdx.y * 32;
  const int col0 = blockIdx.x * 256 + w * 64;

  f32x4 acc[2][4];
  #pragma unroll
  for (int a = 0; a < 2; a++)
    #pragma unroll
    for (int g = 0; g < 4; g++) acc[a][g] = (f32x4){0.f, 0.f, 0.f, 0.f};

  const unsigned short* arow0 = A + (size_t)(row0 + ln) * K;
  const unsigned short* arow1 = A + (size_t)(row0 + 16 + ln) * K;
  const unsigned short* wrow[4];
  int ncol[4];
  #pragma unroll
  for (int nt = 0; nt < 4; ++nt){
    int n = col0 + nt * 16 + ln;
    ncol[nt] = n;
    int nc = n < N ? n : (N - 1);
    wrow[nt] = W + (size_t)nc * K;
  }

  const int nk = K >> 5;
  for (int kt = 0; kt < nk; ++kt){
    const int k = (kt << 5) + lk8;
    short8 a0 = *reinterpret_cast<const short8*>(arow0 + k);
    short8 a1 = *reinterpret_cast<const short8*>(arow1 + k);
    #pragma unroll
    for (int nt = 0; nt < 4; ++nt){
      short8 bf = *reinterpret_cast<const short8*>(wrow[nt] + k);
      acc[0][nt] = __builtin_amdgcn_mfma_f32_16x16x32_bf16(a0, bf, acc[0][nt], 0, 0, 0);
      acc[1][nt] = __builtin_amdgcn_mfma_f32_16x16x32_bf16(a1, bf, acc[1][nt], 0, 0, 0);
    }
  }

  #pragma unroll
  for (int nt = 0; nt < 4; ++nt){
    const int n = ncol[nt];
    if (n >= N) continue;
    const float bv = bias ? bias[n] : 0.0f;
    #pragma unroll
    for (int mt = 0; mt < 2; ++mt){
      const int rbase = row0 + mt * 16 + ((lane >> 4) << 2);
      #pragma unroll
      for (int reg = 0; reg < 4; ++reg){
        const int row = rbase + reg;
        if (row >= M) continue;
        float v = acc[mt][nt][reg] + bv;
        if (act == 1) v = sigm(v);
        if (outB) outB[(size_t)row * N + n] = f2bf(v);
        if (outF) outF[(size_t)row * N + n] = v;
      }
    }
  }
}

// ---------------- pooling + loss ----------------

// dec L1 h history: H1 slots 513+t (t = 0..T-1)
__global__ void pool_kernel(const unsigned short* __restrict__ H1, const int* __restrict__ lengths,
                            unsigned short* __restrict__ pooled){
  int i = blockIdx.x * blockDim.x + threadIdx.x;
  if (i >= B_ * H_) return;
  int b = i >> 9;              // H_=512
  int j = i & (H_ - 1);
  int len = lengths[b]; if (len > T_) len = T_;
  float s = 0.0f;
  for (int t = 0; t < len; ++t)
    s += bf2f(H1[(size_t)(513 + t) * BH + ((size_t)b << 9) + j]);
  pooled[i] = f2bf(s);
}

__global__ void loss_kernel(const float* __restrict__ scores, float* __restrict__ out){
  __shared__ float wsum[4];
  const int w = threadIdx.x >> 6;
  const int lane = threadIdx.x & 63;
  float acc = 0.0f;
  for (int b = w; b < B_; b += 4){
    const float* row = scores + (size_t)b * V_;
    float vals[16];
    float mx = -1e30f;
    #pragma unroll
    for (int i = 0; i < 16; ++i){
      int c = lane + i * 64;
      vals[i] = (c < V_) ? row[c] : -1e30f;
      mx = fmaxf(mx, vals[i]);
    }
    #pragma unroll
    for (int off = 32; off; off >>= 1) mx = fmaxf(mx, __shfl_xor(mx, off));
    float se = 0.0f;
    #pragma unroll
    for (int i = 0; i < 16; ++i){
      int c = lane + i * 64;
      if (c < V_) se += expf(vals[i] - mx);
    }
    #pragma unroll
    for (int off = 32; off; off >>= 1) se += __shfl_xor(se, off);
    float logp = row[END_] - (mx + logf(se));
    acc += logp;
  }
  if (lane == 0) wsum[w] = acc;
  __syncthreads();
  if (threadIdx.x == 0){
    out[0] = -(wsum[0] + wsum[1] + wsum[2] + wsum[3]) / (float)B_;
  }
}

// ---------------- host orchestration ----------------

extern "C" void kernel_launch(void* const* d_in, const int* in_sizes, int n_in,
                              void* d_out, int out_size, void* d_ws, size_t ws_size,
                              hipStream_t stream) {
  const float* source   = (const float*)d_in[0];
  const int*   tgt_ids  = (const int*)  d_in[1];
  const int*   lengths  = (const int*)  d_in[2];
  const float* emb      = (const float*)d_in[3];
  const float* eWih0 = (const float*)d_in[4],  *eWhh0 = (const float*)d_in[5];
  const float* ebih0 = (const float*)d_in[6],  *ebhh0 = (const float*)d_in[7];
  const float* eWih1 = (const float*)d_in[8],  *eWhh1 = (const float*)d_in[9];
  const float* ebih1 = (const float*)d_in[10], *ebhh1 = (const float*)d_in[11];
  const float* dWih0 = (const float*)d_in[12], *dWhh0 = (const float*)d_in[13];
  const float* dbih0 = (const float*)d_in[14], *dbhh0 = (const float*)d_in[15];
  const float* dWih1 = (const float*)d_in[16], *dWhh1 = (const float*)d_in[17];
  const float* dbih1 = (const float*)d_in[18], *dbhh1 = (const float*)d_in[19];
  const float* fcW1 = (const float*)d_in[20], *fcb1 = (const float*)d_in[21];
  const float* fcW2 = (const float*)d_in[22], *fcb2 = (const float*)d_in[23];
  const float* fcW3 = (const float*)d_in[24], *fcb3 = (const float*)d_in[25];

  char* p = (char*)d_ws;
  auto alloc = [&](size_t bytes) -> void* {
    void* r = (void*)p;
    p += (bytes + 255) & ~(size_t)255;
    return r;
  };

  unsigned short* src_bf = (unsigned short*)alloc((size_t)B_ * S_ * D_ * 2);
  unsigned short* tg_bf  = (unsigned short*)alloc((size_t)B_ * T_ * E_ * 2);
  unsigned short* H0 = (unsigned short*)alloc((size_t)547 * BH * 2);  // L0 h history
  unsigned short* H1 = (unsigned short*)alloc((size_t)547 * BH * 2);  // L1 h history
  unsigned short* Wc_e0 = (unsigned short*)alloc((size_t)2048 * 768  * 2);
  unsigned short* Wc_e1 = (unsigned short*)alloc((size_t)2048 * 1024 * 2);
  unsigned short* Wc_d0 = (unsigned short*)alloc((size_t)2048 * 768  * 2);
  unsigned short* Wc_d1 = (unsigned short*)alloc((size_t)2048 * 1024 * 2);
  float* bias_e0 = (float*)alloc(2048 * 4);
  float* bias_e1 = (float*)alloc(2048 * 4);
  float* bias_d0 = (float*)alloc(2048 * 4);
  float* bias_d1 = (float*)alloc(2048 * 4);
  unsigned short* fcW1b = (unsigned short*)alloc((size_t)2560 * 512  * 2);
  unsigned short* fcW2b = (unsigned short*)alloc((size_t)1024 * 2560 * 2);
  unsigned short* fcW3b = (unsigned short*)alloc((size_t)V_ * 1024 * 2);
  unsigned short* pooled = (unsigned short*)alloc((size_t)B_ * H_ * 2);
  unsigned short* x1_bf  = (unsigned short*)alloc((size_t)B_ * 2560 * 2);
  unsigned short* x2_bf  = (unsigned short*)alloc((size_t)B_ * 1024 * 2);
  float* scores = (float*)alloc((size_t)B_ * V_ * 4);
  unsigned* flags = (unsigned*)alloc(4 * 64 * 4);   // 4 groups x 64 u32

  // --- setup / conversions ---
  f2bf_kernel<<<8192, 256, 0, stream>>>(source, src_bf, B_ * S_ * D_);
  embed_kernel<<<(B_ * T_ * E_ + 255) / 256, 256, 0, stream>>>(emb, tgt_ids, tg_bf);
  build_wcat<<<2048, 256, 0, stream>>>(eWih0, eWhh0, Wc_e0, D_);
  build_wcat<<<2048, 256, 0, stream>>>(eWih1, eWhh1, Wc_e1, H_);
  build_wcat<<<2048, 256, 0, stream>>>(dWih0, dWhh0, Wc_d0, E_);
  build_wcat<<<2048, 256, 0, stream>>>(dWih1, dWhh1, Wc_d1, H_);
  build_bias<<<2, 256, 0, stream>>>(ebih0, ebhh0, bias_e0);
  build_bias<<<2, 256, 0, stream>>>(ebih1, ebhh1, bias_e1);
  build_bias<<<2, 256, 0, stream>>>(dbih0, dbhh0, bias_d0);
  build_bias<<<2, 256, 0, stream>>>(dbih1, dbhh1, bias_d1);
  f2bf_kernel<<<4096, 256, 0, stream>>>(fcW1, fcW1b, 2560 * 512);
  f2bf_kernel<<<4096, 256, 0, stream>>>(fcW2, fcW2b, 1024 * 2560);
  f2bf_kernel<<<4096, 256, 0, stream>>>(fcW3, fcW3b, V_ * 1024);

  hipMemsetAsync(H0, 0, (size_t)BH * 2, stream);   // slot 0 = h(-1) = 0
  hipMemsetAsync(H1, 0, (size_t)BH * 2, stream);
  hipMemsetAsync(flags, 0, 4 * 64 * 4, stream);

  // --- persistent RNN: all 4 GRU layers, XCD-clustered groups ---
  rnn_persistent<<<NWG_LAUNCH, 256, 0, stream>>>(
      src_bf, tg_bf, Wc_e0, Wc_e1, Wc_d0, Wc_d1,
      bias_e0, bias_e1, bias_d0, bias_d1,
      H0, H1, flags);

  // --- masked time pooling ---
  pool_kernel<<<(B_ * H_ + 255) / 256, 256, 0, stream>>>(H1, lengths, pooled);

  // --- FC chain ---
  {
    dim3 g1((2560 + 255) / 256, B_ / 32);
    gemm_nt<<<g1, 256, 0, stream>>>(pooled, fcW1b, fcb1, x1_bf, (float*)nullptr,
                                    B_, 2560, 512, 0);
    dim3 g2((1024 + 255) / 256, B_ / 32);
    gemm_nt<<<g2, 256, 0, stream>>>(x1_bf, fcW2b, fcb2, x2_bf, (float*)nullptr,
                                    B_, 1024, 2560, 0);
    dim3 g3((V_ + 255) / 256, B_ / 32);
    gemm_nt<<<g3, 256, 0, stream>>>(x2_bf, fcW3b, fcb3, (unsigned short*)nullptr, scores,
                                    B_, V_, 1024, 1);
  }

  // --- loss ---
  loss_kernel<<<1, 256, 0, stream>>>(scores, (float*)d_out);
}

// Round 12
// 4618.082 us; speedup vs baseline: 1.3203x; 1.3203x over previous
//
#include <hip/hip_runtime.h>
#include <hip/hip_bf16.h>
#include <math.h>

#define B_ 128
#define S_ 512
#define D_ 256
#define H_ 512
#define E_ 256
#define V_ 1002
#define T_ 34
#define END_ 1001
#define NWG_TOTAL 128
#define BH (B_ * H_)     // one h-history slot: 65536 elems (128 KB)
#define GPITCH 20        // gbuf row pitch (dwords), 80B

typedef __attribute__((ext_vector_type(8))) short short8;
typedef __attribute__((ext_vector_type(4))) float f32x4;
typedef __attribute__((ext_vector_type(4))) int i32x4;
typedef unsigned long long u64;

__device__ __forceinline__ float bf2f(unsigned short u){
  union { unsigned int i; float f; } x; x.i = ((unsigned int)u) << 16; return x.f;
}
__device__ __forceinline__ unsigned short f2bf(float f){
  union { float f; unsigned int i; } x; x.f = f;
  unsigned int r = x.i + 0x7fffu + ((x.i >> 16) & 1u);
  return (unsigned short)(r >> 16);
}
__device__ __forceinline__ float sigm(float x){ return 1.0f / (1.0f + expf(-x)); }

// write-through coherent store (reaches coherence point; remote readers'
// cache misses fetch the fresh value -- L2s are NOT snooped, so h stores
// must never be plain write-back)
__device__ __forceinline__ void store_coh8(unsigned short* p, u64 v){
  __hip_atomic_store((u64*)p, v, __ATOMIC_RELAXED, __HIP_MEMORY_SCOPE_AGENT);
}

// wide coherent flag read: one 16B coherence-point load
__device__ __forceinline__ i32x4 load_flags16(const unsigned* p){
  i32x4 r;
  asm volatile("global_load_dwordx4 %0, %1, off sc0 sc1\n\ts_waitcnt vmcnt(0)"
               : "=v"(r) : "v"(p) : "memory");
  return r;
}

// ---------------- conversion / setup kernels ----------------

__global__ void f2bf_kernel(const float* __restrict__ in, unsigned short* __restrict__ out, int n){
  int i = blockIdx.x * blockDim.x + threadIdx.x;
  int stride = gridDim.x * blockDim.x;
  for (; i < n; i += stride) out[i] = f2bf(in[i]);
}

__global__ void embed_kernel(const float* __restrict__ emb, const int* __restrict__ ids,
                             unsigned short* __restrict__ out){
  int i = blockIdx.x * blockDim.x + threadIdx.x;
  if (i >= B_ * T_ * E_) return;
  int bt = i >> 8;              // E_=256
  int e  = i & (E_ - 1);
  out[i] = f2bf(emb[(size_t)ids[bt] * E_ + e]);
}

// Wcat layout: [2048, K], K = Din + H. Row n = g*512 + j:
//   g=0 (r): [Wih_r | Whh_r]   g=1 (z): [Wih_z | Whh_z]
//   g=2 (n_input): [Wih_n | 0] g=3 (n_hidden): [0 | Whh_n]
__global__ void build_wcat(const float* __restrict__ Wih, const float* __restrict__ Whh,
                           unsigned short* __restrict__ Wcat, int Din){
  int K = Din + H_;
  int total = 2048 * K;
  int i = blockIdx.x * blockDim.x + threadIdx.x;
  int stride = gridDim.x * blockDim.x;
  for (; i < total; i += stride){
    int n = i / K, k = i - n * K;
    int g = n >> 9, j = n & 511;
    float v;
    if (g < 2){
      int r = (g << 9) + j;
      v = (k < Din) ? Wih[(size_t)r * Din + k] : Whh[(size_t)r * H_ + (k - Din)];
    } else if (g == 2){
      v = (k < Din) ? Wih[(size_t)(1024 + j) * Din + k] : 0.0f;
    } else {
      v = (k < Din) ? 0.0f : Whh[(size_t)(1024 + j) * H_ + (k - Din)];
    }
    Wcat[i] = f2bf(v);
  }
}

// bias4: [2048] = {bih_r+bhh_r, bih_z+bhh_z, bih_n, bhh_n}
__global__ void build_bias(const float* __restrict__ bih, const float* __restrict__ bhh,
                           float* __restrict__ out){
  int j = blockIdx.x * blockDim.x + threadIdx.x;
  if (j >= 512) return;
  out[j]        = bih[j] + bhh[j];
  out[512 + j]  = bih[512 + j] + bhh[512 + j];
  out[1024 + j] = bih[1024 + j];
  out[1536 + j] = bhh[1024 + j];
}

// ---------------- persistent RNN kernel ----------------
// 128 WGs x 256 threads. WGs 0..63: layer 0 (enc then dec, K=768).
// WGs 64..127: layer 1 (K=1024), consuming H0 history via flag polls.
// All dynamic state is write-once, t-indexed: H0/H1[547] slots
//   (slot 0 = zeros; enc t -> slot t+1; dec t -> 513+t; dec reads 512+t).
// Reads of x AND h are PLAIN CACHED (write-once + first-touch-post-flag,
// proven R10); h stores are write-through coherent; flags via MALL-path.
// K-slices INTERLEAVED across waves (kt = wv + 4j) so each wave has x- and
// h-slices; per round each wave batches its 16 x-loads then 16 h-loads in
// registers, overlaps x-MFMAs with the in-flight h-loads (vmcnt(16) split).
// No LDS staging at all; LDS = gbuf cross-wave K-reduction only.
// h-prev carried in registers (thread owns 1 row x 4 cols).

template<int KT, int XKT>
__device__ __forceinline__ void run_layer(
    float* gbuf,
    const unsigned short* __restrict__ Wc, const float* __restrict__ bias4,
    const unsigned short* __restrict__ Xbase, int x_rs, int x_ts,
    const unsigned short* __restrict__ Hread,  // slot t at Hread + t*BH
    unsigned short* Hwrite,                    // step t writes Hwrite + t*BH
    int T, unsigned round0,
    unsigned* own_flags, int slot,
    unsigned* prod_flags, unsigned prod0,      // nullable
    u64* hprev,
    int jtile, int mh, int wv, int lane)
{
  constexpr int K   = KT * 32;
  constexpr int NSL = KT / 4;          // slices per wave (kt = wv + 4*j)
  constexpr int XQ  = XKT / 4;         // x-slices per wave (j < XQ)
  constexpr int HQ  = NSL - XQ;        // h-slices per wave
  const int tid  = threadIdx.x;
  const int ln   = lane & 15;
  const int lk8  = (lane >> 4) << 3;
  const int base_m = mh * 64;

  // ---- weights: 4 gates x 16 cols, interleaved slices kt = wv + 4j ----
  short8 wreg[4][NSL];
  #pragma unroll
  for (int g = 0; g < 4; ++g)
    #pragma unroll
    for (int j = 0; j < NSL; ++j)
      wreg[g][j] = *reinterpret_cast<const short8*>(
          Wc + (size_t)(g * 512 + jtile * 16 + ln) * K + (size_t)(wv + 4 * j) * 32 + lk8);

  // ---- epilogue ownership: thread = 1 row x 4 cols (one 8B h granule) ----
  const int erow  = tid >> 2;          // 0..63
  const int ecol0 = (tid & 3) << 2;    // 0,4,8,12
  const int ej    = (jtile << 4) + ecol0;
  const int egr   = base_m + erow;
  f32x4 bR, bZ, bNI, bNH;
  #pragma unroll
  for (int c = 0; c < 4; ++c){
    bR[c]  = bias4[ej + c];
    bZ[c]  = bias4[512 + ej + c];
    bNI[c] = bias4[1024 + ej + c];
    bNH[c] = bias4[1536 + ej + c];
  }

  for (int t = 0; t < T; ++t){
    // ---- wait: own group's h[t-1] slot complete + producer x slot ----
    if (wv == 0){
      const unsigned own_t  = round0 + (unsigned)t;
      const unsigned prod_t = prod0 + (unsigned)t + 1u;
      const unsigned* pofs = own_flags + (lane & 7) * 4;
      const unsigned* ppfs = prod_flags ? (prod_flags + (lane & 7) * 4) : nullptr;
      for (;;){
        i32x4 f = load_flags16(pofs);
        bool ok = (unsigned)f.x >= own_t && (unsigned)f.y >= own_t &&
                  (unsigned)f.z >= own_t && (unsigned)f.w >= own_t;
        if (ppfs){
          i32x4 g = load_flags16(ppfs);
          ok = ok && (unsigned)g.x >= prod_t && (unsigned)g.y >= prod_t &&
                     (unsigned)g.z >= prod_t && (unsigned)g.w >= prod_t;
        }
        if (__all(ok)) break;
        __builtin_amdgcn_s_sleep(1);
      }
    }
    __syncthreads();

    const unsigned short* Xt  = Xbase + (size_t)t * x_ts;
    const unsigned short* Hin = Hread + (size_t)t * BH;

    // ---- issue this wave's operand loads: x first (oldest), then h ----
    i32x4 xf[XQ][4], hf[HQ][4];
    #pragma unroll
    for (int j = 0; j < XQ; ++j){
      const int kt = wv + 4 * j;
      #pragma unroll
      for (int mt = 0; mt < 4; ++mt){
        const unsigned short* p = Xt + (size_t)(base_m + mt * 16 + ln) * x_rs + kt * 32 + lk8;
        asm volatile("global_load_dwordx4 %0, %1, off" : "=v"(xf[j][mt]) : "v"(p));
      }
    }
    #pragma unroll
    for (int j = 0; j < HQ; ++j){
      const int kt = wv + 4 * (XQ + j);
      #pragma unroll
      for (int mt = 0; mt < 4; ++mt){
        const unsigned short* p = Hin + (size_t)(base_m + mt * 16 + ln) * H_ + (kt - XKT) * 32 + lk8;
        asm volatile("global_load_dwordx4 %0, %1, off" : "=v"(hf[j][mt]) : "v"(p));
      }
    }

    f32x4 acc[4][4];
    #pragma unroll
    for (int g = 0; g < 4; ++g)
      #pragma unroll
      for (int mt = 0; mt < 4; ++mt) acc[g][mt] = (f32x4){0.f, 0.f, 0.f, 0.f};

    // ---- x-MFMAs overlap the 16 in-flight h loads (HQ*4 == 16) ----
    asm volatile("s_waitcnt vmcnt(16)" ::: "memory");
    __builtin_amdgcn_sched_barrier(0);
    #pragma unroll
    for (int j = 0; j < XQ; ++j)
      #pragma unroll
      for (int g = 0; g < 4; ++g)
        #pragma unroll
        for (int mt = 0; mt < 4; ++mt)
          acc[g][mt] = __builtin_amdgcn_mfma_f32_16x16x32_bf16(
              __builtin_bit_cast(short8, xf[j][mt]), wreg[g][j], acc[g][mt], 0, 0, 0);

    asm volatile("s_waitcnt vmcnt(0)" ::: "memory");
    __builtin_amdgcn_sched_barrier(0);
    #pragma unroll
    for (int j = 0; j < HQ; ++j)
      #pragma unroll
      for (int g = 0; g < 4; ++g)
        #pragma unroll
        for (int mt = 0; mt < 4; ++mt)
          acc[g][mt] = __builtin_amdgcn_mfma_f32_16x16x32_bf16(
              __builtin_bit_cast(short8, hf[j][mt]), wreg[g][XQ + j], acc[g][mt], 0, 0, 0);

    // ---- partial sums to gbuf[wv][g][row][col] ----
    #pragma unroll
    for (int g = 0; g < 4; ++g)
      #pragma unroll
      for (int mt = 0; mt < 4; ++mt){
        const int rl = mt * 16 + ((lane >> 4) << 2);
        #pragma unroll
        for (int i = 0; i < 4; ++i)
          gbuf[((wv * 4 + g) * 64 + rl + i) * GPITCH + ln] = acc[g][mt][i];
      }
    __syncthreads();

    // ---- epilogue: sum K-quarters, GRU nonlinearity; h-prev register ----
    {
      f32x4 p0 = (f32x4){0.f,0.f,0.f,0.f}, p1 = p0, p2 = p0, p3 = p0;
      #pragma unroll
      for (int qq = 0; qq < 4; ++qq){
        p0 += *reinterpret_cast<const f32x4*>(gbuf + ((qq * 4 + 0) * 64 + erow) * GPITCH + ecol0);
        p1 += *reinterpret_cast<const f32x4*>(gbuf + ((qq * 4 + 1) * 64 + erow) * GPITCH + ecol0);
        p2 += *reinterpret_cast<const f32x4*>(gbuf + ((qq * 4 + 2) * 64 + erow) * GPITCH + ecol0);
        p3 += *reinterpret_cast<const f32x4*>(gbuf + ((qq * 4 + 3) * 64 + erow) * GPITCH + ecol0);
      }
      u64 hv = *hprev;
      u64 hb = 0;
      #pragma unroll
      for (int c = 0; c < 4; ++c){
        float rr = sigm(p0[c] + bR[c]);
        float zz = sigm(p1[c] + bZ[c]);
        float nn = tanhf(p2[c] + bNI[c] + rr * (p3[c] + bNH[c]));
        float hp = bf2f((unsigned short)(hv >> (16 * c)));
        float hn = (1.0f - zz) * nn + zz * hp;
        hb |= ((u64)f2bf(hn)) << (16 * c);
      }
      *hprev = hb;
      store_coh8(Hwrite + (size_t)t * BH + ((size_t)egr << 9) + ej, hb);
    }

    // ---- publish: drain the single store, then flag my slot ----
    asm volatile("s_waitcnt vmcnt(0)" ::: "memory");
    __syncthreads();
    if (tid == 0)
      __hip_atomic_store(own_flags + slot, round0 + (unsigned)t + 1u,
                         __ATOMIC_RELAXED, __HIP_MEMORY_SCOPE_AGENT);
  }
}

__global__ __launch_bounds__(256, 1)
void rnn_persistent(
    const unsigned short* __restrict__ src, const unsigned short* __restrict__ tg,
    const unsigned short* __restrict__ Wc_e0, const unsigned short* __restrict__ Wc_e1,
    const unsigned short* __restrict__ Wc_d0, const unsigned short* __restrict__ Wc_d1,
    const float* __restrict__ b_e0, const float* __restrict__ b_e1,
    const float* __restrict__ b_d0, const float* __restrict__ b_d1,
    unsigned short* H0, unsigned short* H1,
    unsigned* flags)
{
  __shared__ __align__(16) float gbuf[16 * 64 * GPITCH];   // 80 KB
  // one-time acquire: clear stale lines (poison / previous replay) from caches
  __builtin_amdgcn_fence(__ATOMIC_ACQUIRE, "agent");
  const int wg = blockIdx.x;
  const int layer = wg >> 6;
  const int gidx = wg & 63;
  const int jtile = gidx & 31, mh = gidx >> 5;
  const int wv = threadIdx.x >> 6, lane = threadIdx.x & 63;
  unsigned* own  = flags + (size_t)((layer << 1) | mh) * 64;
  unsigned* prod = flags + (size_t)mh * 64;     // layer-0 flags of same mh
  u64 hprev = 0;
  if (layer == 0){
    run_layer<24, 8>(gbuf, Wc_e0, b_e0, src, S_ * D_, D_,
                     H0, H0 + BH, S_, 0u, own, jtile, nullptr, 0u, &hprev,
                     jtile, mh, wv, lane);
    run_layer<24, 8>(gbuf, Wc_d0, b_d0, tg, T_ * E_, E_,
                     H0 + (size_t)512 * BH, H0 + (size_t)513 * BH, T_, 512u,
                     own, jtile, nullptr, 0u, &hprev,
                     jtile, mh, wv, lane);
  } else {
    run_layer<32, 16>(gbuf, Wc_e1, b_e1, H0 + BH, H_, BH,
                      H1, H1 + BH, S_, 0u, own, jtile, prod, 0u, &hprev,
                      jtile, mh, wv, lane);
    run_layer<32, 16>(gbuf, Wc_d1, b_d1, H0 + (size_t)513 * BH, H_, BH,
                      H1 + (size_t)512 * BH, H1 + (size_t)513 * BH, T_, 512u,
                      own, jtile, prod, 512u, &hprev,
                      jtile, mh, wv, lane);
  }
}

// ---------------- generic NT GEMM: C = act(A[M,K] @ W[N,K]^T + bias) ----------------
__global__ __launch_bounds__(256)
void gemm_nt(const unsigned short* __restrict__ A, const unsigned short* __restrict__ W,
             const float* __restrict__ bias,
             unsigned short* __restrict__ outB, float* __restrict__ outF,
             int M, int N, int K, int act)
{
  const int w    = threadIdx.x >> 6;
  const int lane = threadIdx.x & 63;
  const int ln   = lane & 15;
  const int lk8  = (lane >> 4) << 3;
  const int row0 = blockIdx.y * 32;
  const int col0 = blockIdx.x * 256 + w * 64;

  f32x4 acc[2][4];
  #pragma unroll
  for (int a = 0; a < 2; a++)
    #pragma unroll
    for (int g = 0; g < 4; g++) acc[a][g] = (f32x4){0.f, 0.f, 0.f, 0.f};

  const unsigned short* arow0 = A + (size_t)(row0 + ln) * K;
  const unsigned short* arow1 = A + (size_t)(row0 + 16 + ln) * K;
  const unsigned short* wrow[4];
  int ncol[4];
  #pragma unroll
  for (int nt = 0; nt < 4; ++nt){
    int n = col0 + nt * 16 + ln;
    ncol[nt] = n;
    int nc = n < N ? n : (N - 1);
    wrow[nt] = W + (size_t)nc * K;
  }

  const int nk = K >> 5;
  for (int kt = 0; kt < nk; ++kt){
    const int k = (kt << 5) + lk8;
    short8 a0 = *reinterpret_cast<const short8*>(arow0 + k);
    short8 a1 = *reinterpret_cast<const short8*>(arow1 + k);
    #pragma unroll
    for (int nt = 0; nt < 4; ++nt){
      short8 bf = *reinterpret_cast<const short8*>(wrow[nt] + k);
      acc[0][nt] = __builtin_amdgcn_mfma_f32_16x16x32_bf16(a0, bf, acc[0][nt], 0, 0, 0);
      acc[1][nt] = __builtin_amdgcn_mfma_f32_16x16x32_bf16(a1, bf, acc[1][nt], 0, 0, 0);
    }
  }

  #pragma unroll
  for (int nt = 0; nt < 4; ++nt){
    const int n = ncol[nt];
    if (n >= N) continue;
    const float bv = bias ? bias[n] : 0.0f;
    #pragma unroll
    for (int mt = 0; mt < 2; ++mt){
      const int rbase = row0 + mt * 16 + ((lane >> 4) << 2);
      #pragma unroll
      for (int reg = 0; reg < 4; ++reg){
        const int row = rbase + reg;
        if (row >= M) continue;
        float v = acc[mt][nt][reg] + bv;
        if (act == 1) v = sigm(v);
        if (outB) outB[(size_t)row * N + n] = f2bf(v);
        if (outF) outF[(size_t)row * N + n] = v;
      }
    }
  }
}

// ---------------- pooling + loss ----------------

// dec L1 h history: H1 slots 513+t (t = 0..T-1)
__global__ void pool_kernel(const unsigned short* __restrict__ H1, const int* __restrict__ lengths,
                            unsigned short* __restrict__ pooled){
  int i = blockIdx.x * blockDim.x + threadIdx.x;
  if (i >= B_ * H_) return;
  int b = i >> 9;              // H_=512
  int j = i & (H_ - 1);
  int len = lengths[b]; if (len > T_) len = T_;
  float s = 0.0f;
  for (int t = 0; t < len; ++t)
    s += bf2f(H1[(size_t)(513 + t) * BH + ((size_t)b << 9) + j]);
  pooled[i] = f2bf(s);
}

__global__ void loss_kernel(const float* __restrict__ scores, float* __restrict__ out){
  __shared__ float wsum[4];
  const int w = threadIdx.x >> 6;
  const int lane = threadIdx.x & 63;
  float acc = 0.0f;
  for (int b = w; b < B_; b += 4){
    const float* row = scores + (size_t)b * V_;
    float vals[16];
    float mx = -1e30f;
    #pragma unroll
    for (int i = 0; i < 16; ++i){
      int c = lane + i * 64;
      vals[i] = (c < V_) ? row[c] : -1e30f;
      mx = fmaxf(mx, vals[i]);
    }
    #pragma unroll
    for (int off = 32; off; off >>= 1) mx = fmaxf(mx, __shfl_xor(mx, off));
    float se = 0.0f;
    #pragma unroll
    for (int i = 0; i < 16; ++i){
      int c = lane + i * 64;
      if (c < V_) se += expf(vals[i] - mx);
    }
    #pragma unroll
    for (int off = 32; off; off >>= 1) se += __shfl_xor(se, off);
    float logp = row[END_] - (mx + logf(se));
    acc += logp;
  }
  if (lane == 0) wsum[w] = acc;
  __syncthreads();
  if (threadIdx.x == 0){
    out[0] = -(wsum[0] + wsum[1] + wsum[2] + wsum[3]) / (float)B_;
  }
}

// ---------------- host orchestration ----------------

extern "C" void kernel_launch(void* const* d_in, const int* in_sizes, int n_in,
                              void* d_out, int out_size, void* d_ws, size_t ws_size,
                              hipStream_t stream) {
  const float* source   = (const float*)d_in[0];
  const int*   tgt_ids  = (const int*)  d_in[1];
  const int*   lengths  = (const int*)  d_in[2];
  const float* emb      = (const float*)d_in[3];
  const float* eWih0 = (const float*)d_in[4],  *eWhh0 = (const float*)d_in[5];
  const float* ebih0 = (const float*)d_in[6],  *ebhh0 = (const float*)d_in[7];
  const float* eWih1 = (const float*)d_in[8],  *eWhh1 = (const float*)d_in[9];
  const float* ebih1 = (const float*)d_in[10], *ebhh1 = (const float*)d_in[11];
  const float* dWih0 = (const float*)d_in[12], *dWhh0 = (const float*)d_in[13];
  const float* dbih0 = (const float*)d_in[14], *dbhh0 = (const float*)d_in[15];
  const float* dWih1 = (const float*)d_in[16], *dWhh1 = (const float*)d_in[17];
  const float* dbih1 = (const float*)d_in[18], *dbhh1 = (const float*)d_in[19];
  const float* fcW1 = (const float*)d_in[20], *fcb1 = (const float*)d_in[21];
  const float* fcW2 = (const float*)d_in[22], *fcb2 = (const float*)d_in[23];
  const float* fcW3 = (const float*)d_in[24], *fcb3 = (const float*)d_in[25];

  char* p = (char*)d_ws;
  auto alloc = [&](size_t bytes) -> void* {
    void* r = (void*)p;
    p += (bytes + 255) & ~(size_t)255;
    return r;
  };

  unsigned short* src_bf = (unsigned short*)alloc((size_t)B_ * S_ * D_ * 2);
  unsigned short* tg_bf  = (unsigned short*)alloc((size_t)B_ * T_ * E_ * 2);
  unsigned short* H0 = (unsigned short*)alloc((size_t)547 * BH * 2);  // L0 h history
  unsigned short* H1 = (unsigned short*)alloc((size_t)547 * BH * 2);  // L1 h history
  unsigned short* Wc_e0 = (unsigned short*)alloc((size_t)2048 * 768  * 2);
  unsigned short* Wc_e1 = (unsigned short*)alloc((size_t)2048 * 1024 * 2);
  unsigned short* Wc_d0 = (unsigned short*)alloc((size_t)2048 * 768  * 2);
  unsigned short* Wc_d1 = (unsigned short*)alloc((size_t)2048 * 1024 * 2);
  float* bias_e0 = (float*)alloc(2048 * 4);
  float* bias_e1 = (float*)alloc(2048 * 4);
  float* bias_d0 = (float*)alloc(2048 * 4);
  float* bias_d1 = (float*)alloc(2048 * 4);
  unsigned short* fcW1b = (unsigned short*)alloc((size_t)2560 * 512  * 2);
  unsigned short* fcW2b = (unsigned short*)alloc((size_t)1024 * 2560 * 2);
  unsigned short* fcW3b = (unsigned short*)alloc((size_t)V_ * 1024 * 2);
  unsigned short* pooled = (unsigned short*)alloc((size_t)B_ * H_ * 2);
  unsigned short* x1_bf  = (unsigned short*)alloc((size_t)B_ * 2560 * 2);
  unsigned short* x2_bf  = (unsigned short*)alloc((size_t)B_ * 1024 * 2);
  float* scores = (float*)alloc((size_t)B_ * V_ * 4);
  unsigned* flags = (unsigned*)alloc(4 * 64 * 4);   // 4 groups x 64 u32

  // --- setup / conversions ---
  f2bf_kernel<<<8192, 256, 0, stream>>>(source, src_bf, B_ * S_ * D_);
  embed_kernel<<<(B_ * T_ * E_ + 255) / 256, 256, 0, stream>>>(emb, tgt_ids, tg_bf);
  build_wcat<<<2048, 256, 0, stream>>>(eWih0, eWhh0, Wc_e0, D_);
  build_wcat<<<2048, 256, 0, stream>>>(eWih1, eWhh1, Wc_e1, H_);
  build_wcat<<<2048, 256, 0, stream>>>(dWih0, dWhh0, Wc_d0, E_);
  build_wcat<<<2048, 256, 0, stream>>>(dWih1, dWhh1, Wc_d1, H_);
  build_bias<<<2, 256, 0, stream>>>(ebih0, ebhh0, bias_e0);
  build_bias<<<2, 256, 0, stream>>>(ebih1, ebhh1, bias_e1);
  build_bias<<<2, 256, 0, stream>>>(dbih0, dbhh0, bias_d0);
  build_bias<<<2, 256, 0, stream>>>(dbih1, dbhh1, bias_d1);
  f2bf_kernel<<<4096, 256, 0, stream>>>(fcW1, fcW1b, 2560 * 512);
  f2bf_kernel<<<4096, 256, 0, stream>>>(fcW2, fcW2b, 1024 * 2560);
  f2bf_kernel<<<4096, 256, 0, stream>>>(fcW3, fcW3b, V_ * 1024);

  hipMemsetAsync(H0, 0, (size_t)BH * 2, stream);   // slot 0 = h(-1) = 0
  hipMemsetAsync(H1, 0, (size_t)BH * 2, stream);
  hipMemsetAsync(flags, 0, 4 * 64 * 4, stream);

  // --- persistent RNN: all 4 GRU layers ---
  rnn_persistent<<<NWG_TOTAL, 256, 0, stream>>>(
      src_bf, tg_bf, Wc_e0, Wc_e1, Wc_d0, Wc_d1,
      bias_e0, bias_e1, bias_d0, bias_d1,
      H0, H1, flags);

  // --- masked time pooling ---
  pool_kernel<<<(B_ * H_ + 255) / 256, 256, 0, stream>>>(H1, lengths, pooled);

  // --- FC chain ---
  {
    dim3 g1((2560 + 255) / 256, B_ / 32);
    gemm_nt<<<g1, 256, 0, stream>>>(pooled, fcW1b, fcb1, x1_bf, (float*)nullptr,
                                    B_, 2560, 512, 0);
    dim3 g2((1024 + 255) / 256, B_ / 32);
    gemm_nt<<<g2, 256, 0, stream>>>(x1_bf, fcW2b, fcb2, x2_bf, (float*)nullptr,
                                    B_, 1024, 2560, 0);
    dim3 g3((V_ + 255) / 256, B_ / 32);
    gemm_nt<<<g3, 256, 0, stream>>>(x2_bf, fcW3b, fcb3, (unsigned short*)nullptr, scores,
                                    B_, V_, 1024, 1);
  }

  // --- loss ---
  loss_kernel<<<1, 256, 0, stream>>>(scores, (float*)d_out);
}

// Round 13
// 4145.185 us; speedup vs baseline: 1.4709x; 1.1141x over previous
//
#include <hip/hip_runtime.h>
#include <hip/hip_bf16.h>
#include <math.h>

#define B_ 128
#define S_ 512
#define D_ 256
#define H_ 512
#define E_ 256
#define V_ 1002
#define T_ 34
#define END_ 1001
#define NWG_TOTAL 128
#define BH (B_ * H_)     // one h-history slot: 65536 elems (128 KB)
#define GPITCH 20        // gbuf row pitch (dwords), 80B

typedef __attribute__((ext_vector_type(8))) short short8;
typedef __attribute__((ext_vector_type(4))) float f32x4;
typedef __attribute__((ext_vector_type(4))) int i32x4;
typedef unsigned long long u64;

__device__ __forceinline__ float bf2f(unsigned short u){
  union { unsigned int i; float f; } x; x.i = ((unsigned int)u) << 16; return x.f;
}
__device__ __forceinline__ unsigned short f2bf(float f){
  union { float f; unsigned int i; } x; x.f = f;
  unsigned int r = x.i + 0x7fffu + ((x.i >> 16) & 1u);
  return (unsigned short)(r >> 16);
}
__device__ __forceinline__ float sigm(float x){ return 1.0f / (1.0f + expf(-x)); }

// write-through coherent store (cross-XCD visible; L2s are not snooped)
__device__ __forceinline__ void store_coh8(unsigned short* p, u64 v){
  __hip_atomic_store((u64*)p, v, __ATOMIC_RELAXED, __HIP_MEMORY_SCOPE_AGENT);
}

// wide coherent flag read: one 16B coherence-point load.
// NOTE: embedded vmcnt(0) also drains any in-flight operand loads -- used
// deliberately to overlap x-loads with the poll window.
__device__ __forceinline__ i32x4 load_flags16(const unsigned* p){
  i32x4 r;
  asm volatile("global_load_dwordx4 %0, %1, off sc0 sc1\n\ts_waitcnt vmcnt(0)"
               : "=v"(r) : "v"(p) : "memory");
  return r;
}

// ---------------- conversion / setup kernels ----------------

__global__ void f2bf_kernel(const float* __restrict__ in, unsigned short* __restrict__ out, int n){
  int i = blockIdx.x * blockDim.x + threadIdx.x;
  int stride = gridDim.x * blockDim.x;
  for (; i < n; i += stride) out[i] = f2bf(in[i]);
}

__global__ void embed_kernel(const float* __restrict__ emb, const int* __restrict__ ids,
                             unsigned short* __restrict__ out){
  int i = blockIdx.x * blockDim.x + threadIdx.x;
  if (i >= B_ * T_ * E_) return;
  int bt = i >> 8;              // E_=256
  int e  = i & (E_ - 1);
  out[i] = f2bf(emb[(size_t)ids[bt] * E_ + e]);
}

// Wcat layout: [2048, K], K = Din + H. Row n = g*512 + j:
//   g=0 (r): [Wih_r | Whh_r]   g=1 (z): [Wih_z | Whh_z]
//   g=2 (n_input): [Wih_n | 0] g=3 (n_hidden): [0 | Whh_n]
__global__ void build_wcat(const float* __restrict__ Wih, const float* __restrict__ Whh,
                           unsigned short* __restrict__ Wcat, int Din){
  int K = Din + H_;
  int total = 2048 * K;
  int i = blockIdx.x * blockDim.x + threadIdx.x;
  int stride = gridDim.x * blockDim.x;
  for (; i < total; i += stride){
    int n = i / K, k = i - n * K;
    int g = n >> 9, j = n & 511;
    float v;
    if (g < 2){
      int r = (g << 9) + j;
      v = (k < Din) ? Wih[(size_t)r * Din + k] : Whh[(size_t)r * H_ + (k - Din)];
    } else if (g == 2){
      v = (k < Din) ? Wih[(size_t)(1024 + j) * Din + k] : 0.0f;
    } else {
      v = (k < Din) ? 0.0f : Whh[(size_t)(1024 + j) * H_ + (k - Din)];
    }
    Wcat[i] = f2bf(v);
  }
}

// bias4: [2048] = {bih_r+bhh_r, bih_z+bhh_z, bih_n, bhh_n}
__global__ void build_bias(const float* __restrict__ bih, const float* __restrict__ bhh,
                           float* __restrict__ out){
  int j = blockIdx.x * blockDim.x + threadIdx.x;
  if (j >= 512) return;
  out[j]        = bih[j] + bhh[j];
  out[512 + j]  = bih[512 + j] + bhh[512 + j];
  out[1024 + j] = bih[1024 + j];
  out[1536 + j] = bhh[1024 + j];
}

// ---------------- persistent RNN kernel ----------------
// 128 WGs x 256 threads. WGs 0..63: layer 0 (enc then dec, K=768).
// WGs 64..127: layer 1 (K=1024), consuming H0 history via flag polls.
// Write-once t-indexed histories H0/H1[547] (slot 0 zeros; enc t -> t+1;
// dec t -> 513+t; dec reads 512+t). x/h reads plain cached (write-once +
// first-touch-post-flag); h stores write-through coherent; flags MALL-path.
// ROUND STRUCTURE (critical-path surgery): issue x-loads FIRST; all waves
// independently poll own-group flags (poll's vmcnt drains x); issue h-loads;
// x-MFMAs overlap the in-flight h; vmcnt(0); h-MFMAs; gbuf reduce; epilogue.
// K-slices interleaved across waves (kt = wv + 4j). LDS = gbuf only.
// h-prev carried in registers (thread owns 1 row x 4 cols).

template<int KT, int XKT>
__device__ __forceinline__ void run_layer(
    float* gbuf,
    const unsigned short* __restrict__ Wc, const float* __restrict__ bias4,
    const unsigned short* __restrict__ Xbase, int x_rs, int x_ts,
    const unsigned short* __restrict__ Hread,  // slot t at Hread + t*BH
    unsigned short* Hwrite,                    // step t writes Hwrite + t*BH
    int T, unsigned round0,
    unsigned* own_flags, int slot,
    unsigned* prod_flags, unsigned prod0,      // nullable
    u64* hprev,
    int jtile, int mh, int wv, int lane)
{
  constexpr int K   = KT * 32;
  constexpr int NSL = KT / 4;          // slices per wave (kt = wv + 4*j)
  constexpr int XQ  = XKT / 4;         // x-slices per wave (j < XQ)
  constexpr int HQ  = NSL - XQ;        // h-slices per wave
  const int tid  = threadIdx.x;
  const int ln   = lane & 15;
  const int lk8  = (lane >> 4) << 3;
  const int base_m = mh * 64;

  // ---- weights: 4 gates x 16 cols, interleaved slices kt = wv + 4j ----
  short8 wreg[4][NSL];
  #pragma unroll
  for (int g = 0; g < 4; ++g)
    #pragma unroll
    for (int j = 0; j < NSL; ++j)
      wreg[g][j] = *reinterpret_cast<const short8*>(
          Wc + (size_t)(g * 512 + jtile * 16 + ln) * K + (size_t)(wv + 4 * j) * 32 + lk8);

  // ---- epilogue ownership: thread = 1 row x 4 cols (one 8B h granule) ----
  const int erow  = tid >> 2;          // 0..63
  const int ecol0 = (tid & 3) << 2;    // 0,4,8,12
  const int ej    = (jtile << 4) + ecol0;
  const int egr   = base_m + erow;
  f32x4 bR, bZ, bNI, bNH;
  #pragma unroll
  for (int c = 0; c < 4; ++c){
    bR[c]  = bias4[ej + c];
    bZ[c]  = bias4[512 + ej + c];
    bNI[c] = bias4[1024 + ej + c];
    bNH[c] = bias4[1536 + ej + c];
  }

  const unsigned* pofs = own_flags + (lane & 7) * 4;
  const unsigned* ppfs = prod_flags ? (prod_flags + (lane & 7) * 4) : nullptr;

  for (int t = 0; t < T; ++t){
    const unsigned short* Xt  = Xbase + (size_t)t * x_ts;
    const unsigned short* Hin = Hread + (size_t)t * BH;

    // ---- L1 only: gate x on producer slot (usually already set) ----
    if (ppfs){
      const unsigned prod_t = prod0 + (unsigned)t + 1u;
      for (;;){
        i32x4 g = load_flags16(ppfs);
        bool ok = (unsigned)g.x >= prod_t && (unsigned)g.y >= prod_t &&
                  (unsigned)g.z >= prod_t && (unsigned)g.w >= prod_t;
        if (__all(ok)) break;
        __builtin_amdgcn_s_sleep(1);
      }
      __builtin_amdgcn_sched_barrier(0);
    }

    // ---- issue x loads immediately (static / producer-gated data) ----
    i32x4 xf[XQ][4], hf[HQ][4];
    #pragma unroll
    for (int j = 0; j < XQ; ++j){
      const int kt = wv + 4 * j;
      #pragma unroll
      for (int mt = 0; mt < 4; ++mt){
        const unsigned short* p = Xt + (size_t)(base_m + mt * 16 + ln) * x_rs + kt * 32 + lk8;
        asm volatile("global_load_dwordx4 %0, %1, off" : "=v"(xf[j][mt]) : "v"(p));
      }
    }

    // ---- own-group wait (all waves poll; drains x loads as side effect) ----
    {
      const unsigned own_t = round0 + (unsigned)t;
      for (;;){
        i32x4 f = load_flags16(pofs);
        bool ok = (unsigned)f.x >= own_t && (unsigned)f.y >= own_t &&
                  (unsigned)f.z >= own_t && (unsigned)f.w >= own_t;
        if (__all(ok)) break;
        __builtin_amdgcn_s_sleep(1);
      }
      __builtin_amdgcn_sched_barrier(0);
    }

    // ---- issue h loads; x-MFMAs overlap the in-flight h ----
    #pragma unroll
    for (int j = 0; j < HQ; ++j){
      const int kt = wv + 4 * (XQ + j);
      #pragma unroll
      for (int mt = 0; mt < 4; ++mt){
        const unsigned short* p = Hin + (size_t)(base_m + mt * 16 + ln) * H_ + (kt - XKT) * 32 + lk8;
        asm volatile("global_load_dwordx4 %0, %1, off" : "=v"(hf[j][mt]) : "v"(p));
      }
    }
    __builtin_amdgcn_sched_barrier(0);

    f32x4 acc[4][4];
    #pragma unroll
    for (int g = 0; g < 4; ++g)
      #pragma unroll
      for (int mt = 0; mt < 4; ++mt) acc[g][mt] = (f32x4){0.f, 0.f, 0.f, 0.f};

    #pragma unroll
    for (int j = 0; j < XQ; ++j)
      #pragma unroll
      for (int g = 0; g < 4; ++g)
        #pragma unroll
        for (int mt = 0; mt < 4; ++mt)
          acc[g][mt] = __builtin_amdgcn_mfma_f32_16x16x32_bf16(
              __builtin_bit_cast(short8, xf[j][mt]), wreg[g][j], acc[g][mt], 0, 0, 0);

    asm volatile("s_waitcnt vmcnt(0)" ::: "memory");
    __builtin_amdgcn_sched_barrier(0);
    #pragma unroll
    for (int j = 0; j < HQ; ++j)
      #pragma unroll
      for (int g = 0; g < 4; ++g)
        #pragma unroll
        for (int mt = 0; mt < 4; ++mt)
          acc[g][mt] = __builtin_amdgcn_mfma_f32_16x16x32_bf16(
              __builtin_bit_cast(short8, hf[j][mt]), wreg[g][XQ + j], acc[g][mt], 0, 0, 0);

    // ---- partial sums to gbuf[wv][g][row][col] ----
    #pragma unroll
    for (int g = 0; g < 4; ++g)
      #pragma unroll
      for (int mt = 0; mt < 4; ++mt){
        const int rl = mt * 16 + ((lane >> 4) << 2);
        #pragma unroll
        for (int i = 0; i < 4; ++i)
          gbuf[((wv * 4 + g) * 64 + rl + i) * GPITCH + ln] = acc[g][mt][i];
      }
    __syncthreads();

    // ---- epilogue: sum K-quarters, GRU nonlinearity; h-prev register ----
    {
      f32x4 p0 = (f32x4){0.f,0.f,0.f,0.f}, p1 = p0, p2 = p0, p3 = p0;
      #pragma unroll
      for (int qq = 0; qq < 4; ++qq){
        p0 += *reinterpret_cast<const f32x4*>(gbuf + ((qq * 4 + 0) * 64 + erow) * GPITCH + ecol0);
        p1 += *reinterpret_cast<const f32x4*>(gbuf + ((qq * 4 + 1) * 64 + erow) * GPITCH + ecol0);
        p2 += *reinterpret_cast<const f32x4*>(gbuf + ((qq * 4 + 2) * 64 + erow) * GPITCH + ecol0);
        p3 += *reinterpret_cast<const f32x4*>(gbuf + ((qq * 4 + 3) * 64 + erow) * GPITCH + ecol0);
      }
      u64 hv = *hprev;
      u64 hb = 0;
      #pragma unroll
      for (int c = 0; c < 4; ++c){
        float rr = sigm(p0[c] + bR[c]);
        float zz = sigm(p1[c] + bZ[c]);
        float nn = tanhf(p2[c] + bNI[c] + rr * (p3[c] + bNH[c]));
        float hp = bf2f((unsigned short)(hv >> (16 * c)));
        float hn = (1.0f - zz) * nn + zz * hp;
        hb |= ((u64)f2bf(hn)) << (16 * c);
      }
      *hprev = hb;
      store_coh8(Hwrite + (size_t)t * BH + ((size_t)egr << 9) + ej, hb);
    }

    // ---- publish: drain the single store, then flag my slot ----
    asm volatile("s_waitcnt vmcnt(0)" ::: "memory");
    __syncthreads();
    if (tid == 0)
      __hip_atomic_store(own_flags + slot, round0 + (unsigned)t + 1u,
                         __ATOMIC_RELAXED, __HIP_MEMORY_SCOPE_AGENT);
  }
}

__global__ __launch_bounds__(256, 1)
void rnn_persistent(
    const unsigned short* __restrict__ src, const unsigned short* __restrict__ tg,
    const unsigned short* __restrict__ Wc_e0, const unsigned short* __restrict__ Wc_e1,
    const unsigned short* __restrict__ Wc_d0, const unsigned short* __restrict__ Wc_d1,
    const float* __restrict__ b_e0, const float* __restrict__ b_e1,
    const float* __restrict__ b_d0, const float* __restrict__ b_d1,
    unsigned short* H0, unsigned short* H1,
    unsigned* flags)
{
  __shared__ __align__(16) float gbuf[16 * 64 * GPITCH];   // 80 KB
  // one-time acquire: clear stale lines (poison / previous replay) from caches
  __builtin_amdgcn_fence(__ATOMIC_ACQUIRE, "agent");
  const int wg = blockIdx.x;
  const int layer = wg >> 6;
  const int gidx = wg & 63;
  const int jtile = gidx & 31, mh = gidx >> 5;
  const int wv = threadIdx.x >> 6, lane = threadIdx.x & 63;
  unsigned* own  = flags + (size_t)((layer << 1) | mh) * 64;
  unsigned* prod = flags + (size_t)mh * 64;     // layer-0 flags of same mh
  u64 hprev = 0;
  if (layer == 0){
    run_layer<24, 8>(gbuf, Wc_e0, b_e0, src, S_ * D_, D_,
                     H0, H0 + BH, S_, 0u, own, jtile, nullptr, 0u, &hprev,
                     jtile, mh, wv, lane);
    run_layer<24, 8>(gbuf, Wc_d0, b_d0, tg, T_ * E_, E_,
                     H0 + (size_t)512 * BH, H0 + (size_t)513 * BH, T_, 512u,
                     own, jtile, nullptr, 0u, &hprev,
                     jtile, mh, wv, lane);
  } else {
    run_layer<32, 16>(gbuf, Wc_e1, b_e1, H0 + BH, H_, BH,
                      H1, H1 + BH, S_, 0u, own, jtile, prod, 0u, &hprev,
                      jtile, mh, wv, lane);
    run_layer<32, 16>(gbuf, Wc_d1, b_d1, H0 + (size_t)513 * BH, H_, BH,
                      H1 + (size_t)512 * BH, H1 + (size_t)513 * BH, T_, 512u,
                      own, jtile, prod, 512u, &hprev,
                      jtile, mh, wv, lane);
  }
}

// ---------------- generic NT GEMM: C = act(A[M,K] @ W[N,K]^T + bias) ----------------
__global__ __launch_bounds__(256)
void gemm_nt(const unsigned short* __restrict__ A, const unsigned short* __restrict__ W,
             const float* __restrict__ bias,
             unsigned short* __restrict__ outB, float* __restrict__ outF,
             int M, int N, int K, int act)
{
  const int w    = threadIdx.x >> 6;
  const int lane = threadIdx.x & 63;
  const int ln   = lane & 15;
  const int lk8  = (lane >> 4) << 3;
  const int row0 = blockIdx.y * 32;
  const int col0 = blockIdx.x * 256 + w * 64;

  f32x4 acc[2][4];
  #pragma unroll
  for (int a = 0; a < 2; a++)
    #pragma unroll
    for (int g = 0; g < 4; g++) acc[a][g] = (f32x4){0.f, 0.f, 0.f, 0.f};

  const unsigned short* arow0 = A + (size_t)(row0 + ln) * K;
  const unsigned short* arow1 = A + (size_t)(row0 + 16 + ln) * K;
  const unsigned short* wrow[4];
  int ncol[4];
  #pragma unroll
  for (int nt = 0; nt < 4; ++nt){
    int n = col0 + nt * 16 + ln;
    ncol[nt] = n;
    int nc = n < N ? n : (N - 1);
    wrow[nt] = W + (size_t)nc * K;
  }

  const int nk = K >> 5;
  for (int kt = 0; kt < nk; ++kt){
    const int k = (kt << 5) + lk8;
    short8 a0 = *reinterpret_cast<const short8*>(arow0 + k);
    short8 a1 = *reinterpret_cast<const short8*>(arow1 + k);
    #pragma unroll
    for (int nt = 0; nt < 4; ++nt){
      short8 bf = *reinterpret_cast<const short8*>(wrow[nt] + k);
      acc[0][nt] = __builtin_amdgcn_mfma_f32_16x16x32_bf16(a0, bf, acc[0][nt], 0, 0, 0);
      acc[1][nt] = __builtin_amdgcn_mfma_f32_16x16x32_bf16(a1, bf, acc[1][nt], 0, 0, 0);
    }
  }

  #pragma unroll
  for (int nt = 0; nt < 4; ++nt){
    const int n = ncol[nt];
    if (n >= N) continue;
    const float bv = bias ? bias[n] : 0.0f;
    #pragma unroll
    for (int mt = 0; mt < 2; ++mt){
      const int rbase = row0 + mt * 16 + ((lane >> 4) << 2);
      #pragma unroll
      for (int reg = 0; reg < 4; ++reg){
        const int row = rbase + reg;
        if (row >= M) continue;
        float v = acc[mt][nt][reg] + bv;
        if (act == 1) v = sigm(v);
        if (outB) outB[(size_t)row * N + n] = f2bf(v);
        if (outF) outF[(size_t)row * N + n] = v;
      }
    }
  }
}

// ---------------- pooling + loss ----------------

// dec L1 h history: H1 slots 513+t (t = 0..T-1)
__global__ void pool_kernel(const unsigned short* __restrict__ H1, const int* __restrict__ lengths,
                            unsigned short* __restrict__ pooled){
  int i = blockIdx.x * blockDim.x + threadIdx.x;
  if (i >= B_ * H_) return;
  int b = i >> 9;              // H_=512
  int j = i & (H_ - 1);
  int len = lengths[b]; if (len > T_) len = T_;
  float s = 0.0f;
  for (int t = 0; t < len; ++t)
    s += bf2f(H1[(size_t)(513 + t) * BH + ((size_t)b << 9) + j]);
  pooled[i] = f2bf(s);
}

__global__ void loss_kernel(const float* __restrict__ scores, float* __restrict__ out){
  __shared__ float wsum[4];
  const int w = threadIdx.x >> 6;
  const int lane = threadIdx.x & 63;
  float acc = 0.0f;
  for (int b = w; b < B_; b += 4){
    const float* row = scores + (size_t)b * V_;
    float vals[16];
    float mx = -1e30f;
    #pragma unroll
    for (int i = 0; i < 16; ++i){
      int c = lane + i * 64;
      vals[i] = (c < V_) ? row[c] : -1e30f;
      mx = fmaxf(mx, vals[i]);
    }
    #pragma unroll
    for (int off = 32; off; off >>= 1) mx = fmaxf(mx, __shfl_xor(mx, off));
    float se = 0.0f;
    #pragma unroll
    for (int i = 0; i < 16; ++i){
      int c = lane + i * 64;
      if (c < V_) se += expf(vals[i] - mx);
    }
    #pragma unroll
    for (int off = 32; off; off >>= 1) se += __shfl_xor(se, off);
    float logp = row[END_] - (mx + logf(se));
    acc += logp;
  }
  if (lane == 0) wsum[w] = acc;
  __syncthreads();
  if (threadIdx.x == 0){
    out[0] = -(wsum[0] + wsum[1] + wsum[2] + wsum[3]) / (float)B_;
  }
}

// ---------------- host orchestration ----------------

extern "C" void kernel_launch(void* const* d_in, const int* in_sizes, int n_in,
                              void* d_out, int out_size, void* d_ws, size_t ws_size,
                              hipStream_t stream) {
  const float* source   = (const float*)d_in[0];
  const int*   tgt_ids  = (const int*)  d_in[1];
  const int*   lengths  = (const int*)  d_in[2];
  const float* emb      = (const float*)d_in[3];
  const float* eWih0 = (const float*)d_in[4],  *eWhh0 = (const float*)d_in[5];
  const float* ebih0 = (const float*)d_in[6],  *ebhh0 = (const float*)d_in[7];
  const float* eWih1 = (const float*)d_in[8],  *eWhh1 = (const float*)d_in[9];
  const float* ebih1 = (const float*)d_in[10], *ebhh1 = (const float*)d_in[11];
  const float* dWih0 = (const float*)d_in[12], *dWhh0 = (const float*)d_in[13];
  const float* dbih0 = (const float*)d_in[14], *dbhh0 = (const float*)d_in[15];
  const float* dWih1 = (const float*)d_in[16], *dWhh1 = (const float*)d_in[17];
  const float* dbih1 = (const float*)d_in[18], *dbhh1 = (const float*)d_in[19];
  const float* fcW1 = (const float*)d_in[20], *fcb1 = (const float*)d_in[21];
  const float* fcW2 = (const float*)d_in[22], *fcb2 = (const float*)d_in[23];
  const float* fcW3 = (const float*)d_in[24], *fcb3 = (const float*)d_in[25];

  char* p = (char*)d_ws;
  auto alloc = [&](size_t bytes) -> void* {
    void* r = (void*)p;
    p += (bytes + 255) & ~(size_t)255;
    return r;
  };

  unsigned short* src_bf = (unsigned short*)alloc((size_t)B_ * S_ * D_ * 2);
  unsigned short* tg_bf  = (unsigned short*)alloc((size_t)B_ * T_ * E_ * 2);
  unsigned short* H0 = (unsigned short*)alloc((size_t)547 * BH * 2);  // L0 h history
  unsigned short* H1 = (unsigned short*)alloc((size_t)547 * BH * 2);  // L1 h history
  unsigned short* Wc_e0 = (unsigned short*)alloc((size_t)2048 * 768  * 2);
  unsigned short* Wc_e1 = (unsigned short*)alloc((size_t)2048 * 1024 * 2);
  unsigned short* Wc_d0 = (unsigned short*)alloc((size_t)2048 * 768  * 2);
  unsigned short* Wc_d1 = (unsigned short*)alloc((size_t)2048 * 1024 * 2);
  float* bias_e0 = (float*)alloc(2048 * 4);
  float* bias_e1 = (float*)alloc(2048 * 4);
  float* bias_d0 = (float*)alloc(2048 * 4);
  float* bias_d1 = (float*)alloc(2048 * 4);
  unsigned short* fcW1b = (unsigned short*)alloc((size_t)2560 * 512  * 2);
  unsigned short* fcW2b = (unsigned short*)alloc((size_t)1024 * 2560 * 2);
  unsigned short* fcW3b = (unsigned short*)alloc((size_t)V_ * 1024 * 2);
  unsigned short* pooled = (unsigned short*)alloc((size_t)B_ * H_ * 2);
  unsigned short* x1_bf  = (unsigned short*)alloc((size_t)B_ * 2560 * 2);
  unsigned short* x2_bf  = (unsigned short*)alloc((size_t)B_ * 1024 * 2);
  float* scores = (float*)alloc((size_t)B_ * V_ * 4);
  unsigned* flags = (unsigned*)alloc(4 * 64 * 4);   // 4 groups x 64 u32

  // --- setup / conversions ---
  f2bf_kernel<<<8192, 256, 0, stream>>>(source, src_bf, B_ * S_ * D_);
  embed_kernel<<<(B_ * T_ * E_ + 255) / 256, 256, 0, stream>>>(emb, tgt_ids, tg_bf);
  build_wcat<<<2048, 256, 0, stream>>>(eWih0, eWhh0, Wc_e0, D_);
  build_wcat<<<2048, 256, 0, stream>>>(eWih1, eWhh1, Wc_e1, H_);
  build_wcat<<<2048, 256, 0, stream>>>(dWih0, dWhh0, Wc_d0, E_);
  build_wcat<<<2048, 256, 0, stream>>>(dWih1, dWhh1, Wc_d1, H_);
  build_bias<<<2, 256, 0, stream>>>(ebih0, ebhh0, bias_e0);
  build_bias<<<2, 256, 0, stream>>>(ebih1, ebhh1, bias_e1);
  build_bias<<<2, 256, 0, stream>>>(dbih0, dbhh0, bias_d0);
  build_bias<<<2, 256, 0, stream>>>(dbih1, dbhh1, bias_d1);
  f2bf_kernel<<<4096, 256, 0, stream>>>(fcW1, fcW1b, 2560 * 512);
  f2bf_kernel<<<4096, 256, 0, stream>>>(fcW2, fcW2b, 1024 * 2560);
  f2bf_kernel<<<4096, 256, 0, stream>>>(fcW3, fcW3b, V_ * 1024);

  hipMemsetAsync(H0, 0, (size_t)BH * 2, stream);   // slot 0 = h(-1) = 0
  hipMemsetAsync(H1, 0, (size_t)BH * 2, stream);
  hipMemsetAsync(flags, 0, 4 * 64 * 4, stream);

  // --- persistent RNN: all 4 GRU layers ---
  rnn_persistent<<<NWG_TOTAL, 256, 0, stream>>>(
      src_bf, tg_bf, Wc_e0, Wc_e1, Wc_d0, Wc_d1,
      bias_e0, bias_e1, bias_d0, bias_d1,
      H0, H1, flags);

  // --- masked time pooling ---
  pool_kernel<<<(B_ * H_ + 255) / 256, 256, 0, stream>>>(H1, lengths, pooled);

  // --- FC chain ---
  {
    dim3 g1((2560 + 255) / 256, B_ / 32);
    gemm_nt<<<g1, 256, 0, stream>>>(pooled, fcW1b, fcb1, x1_bf, (float*)nullptr,
                                    B_, 2560, 512, 0);
    dim3 g2((1024 + 255) / 256, B_ / 32);
    gemm_nt<<<g2, 256, 0, stream>>>(x1_bf, fcW2b, fcb2, x2_bf, (float*)nullptr,
                                    B_, 1024, 2560, 0);
    dim3 g3((V_ + 255) / 256, B_ / 32);
    gemm_nt<<<g3, 256, 0, stream>>>(x2_bf, fcW3b, fcb3, (unsigned short*)nullptr, scores,
                                    B_, V_, 1024, 1);
  }

  // --- loss ---
  loss_kernel<<<1, 256, 0, stream>>>(scores, (float*)d_out);
}